// Round 11
// baseline (5644.567 us; speedup 1.0000x reference)
//
#include <hip/hip_runtime.h>

typedef _Float16 f16;
typedef _Float16 f16x8 __attribute__((ext_vector_type(8)));
typedef _Float16 f16x4 __attribute__((ext_vector_type(4)));
typedef float    f32x4 __attribute__((ext_vector_type(4)));

#define T_STEPS 256
#define B_ROWS  128
#define I_DIM   1024
#define H_DIM   1024
#define O_DIM   512
#define TBROWS  (T_STEPS * B_ROWS)   // 32768
#define BH      (B_ROWS * H_DIM)     // 131072
#define NWG     64

// ---------------- init: zero flag + agg arrays (REQUIRED each launch:
// 0xAA poison would compare >= gen and fake-pass the polls) ----------------
__global__ void k_init(unsigned* flg) {
    for (int i = threadIdx.x; i < (8 * NWG + 8) * 16; i += 256) flg[i] = 0u;
}

// ---------- cached load (L1+L2). Safe: every handoff address is
// first-touched AFTER its producer's MALL write (step-indexed buffers,
// dispatch-start acquire invalidated all L2s; prior-replay stale lines
// hold the same deterministic values). ----------
template<int K>
__device__ __forceinline__ f16x8 gload(const f16* p) {
    f16x8 r;
    asm volatile("global_load_dwordx4 %0, %1, off offset:%c2"
                 : "=v"(r) : "v"(p), "n"(K * 64));
    return r;
}
template<int K> struct Iss {
    static __device__ __forceinline__ void go(f16x8* fr, const f16* p) {
        fr[K] = gload<K>(p);
        Iss<K + 1>::go(fr, p);
    }
};
template<> struct Iss<32> {
    static __device__ __forceinline__ void go(f16x8*, const f16*) {}
};
// write-through to MALL (cross-XCD visible; no write-back false sharing)
__device__ __forceinline__ void gstore8_cc(f16* p, f16x4 v) {
    asm volatile("global_store_dwordx2 %0, %1, off sc0 sc1"
                 :: "v"(p), "v"(v) : "memory");
}

// ---------- hierarchical per-row-group wave barrier ----------
// Publish: own-wave vmcnt(0) (drains exchange-store ack AND the gate
// prefetch issued just before it — ack latency hidden under the load),
// lane0 writes flag[w][wg] (64B-padded line).
// Wait: aggregator wave (wg == grp) scans the 64 producer flags and
// publishes one combined flag agg[grp]; other waves poll only agg[grp].
__device__ __forceinline__ void wpub(unsigned* flg, int grp, int wg, unsigned gen, int lane) {
    asm volatile("s_waitcnt vmcnt(0) lgkmcnt(0)" ::: "memory");
    if (lane == 0)
        __hip_atomic_store(&flg[(grp * NWG + wg) * 16], gen, __ATOMIC_RELAXED, __HIP_MEMORY_SCOPE_AGENT);
    __builtin_amdgcn_sched_barrier(0);
}
__device__ __forceinline__ void wpoll(unsigned* flg, unsigned* agg, int grp, int wg, unsigned gen, int lane) {
    if (wg == grp) {
        while (__hip_atomic_load(&flg[(grp * NWG + lane) * 16], __ATOMIC_RELAXED, __HIP_MEMORY_SCOPE_AGENT) < gen)
            __builtin_amdgcn_s_sleep(1);
        if (lane < 2)
            __hip_atomic_store(&agg[grp * 16 + lane], gen, __ATOMIC_RELAXED, __HIP_MEMORY_SCOPE_AGENT);
    } else {
        while (__hip_atomic_load(&agg[grp * 16 + (lane & 1)], __ATOMIC_RELAXED, __HIP_MEMORY_SCOPE_AGENT) < gen)
            __builtin_amdgcn_s_sleep(1);
    }
    __builtin_amdgcn_sched_barrier(0);
}

// ---------------- gate GEMM: G_g = (x + noise_g) @ Wx_g^T  (fp16 out) ----------------
__global__ __launch_bounds__(256) void k_gate_gemm(
    const float* __restrict__ x,
    const float* __restrict__ nR, const float* __restrict__ nZ, const float* __restrict__ nH,
    const float* __restrict__ WxR, const float* __restrict__ WxZ, const float* __restrict__ WxH,
    f16* __restrict__ GR, f16* __restrict__ GZ, f16* __restrict__ GH)
{
    const int g = blockIdx.z;
    const float* noise = (g == 0) ? nR : (g == 1) ? nZ : nH;
    const float* W     = (g == 0) ? WxR : (g == 1) ? WxZ : WxH;
    f16* G             = (g == 0) ? GR : (g == 1) ? GZ : GH;

    __shared__ f16 As[128 * 40];
    __shared__ f16 Bs[128 * 40];

    const int t = threadIdx.x;
    const int lane = t & 63;
    const int w  = t >> 6;
    const int wm = w & 1, wn = w >> 1;
    const int rowBase = blockIdx.x * 128;
    const int colBase = blockIdx.y * 128;

    const int srow = t >> 1;
    const int sk   = (t & 1) * 16;

    f32x4 acc[4][4] = {};

    for (int kt = 0; kt < I_DIM; kt += 32) {
        {
            const float* xp = x     + (size_t)(rowBase + srow) * I_DIM + kt + sk;
            const float* np = noise + (size_t)(rowBase + srow) * I_DIM + kt + sk;
            f16x8 t0, t1;
            #pragma unroll
            for (int q = 0; q < 2; ++q) {
                float4 a = ((const float4*)xp)[q];
                float4 b = ((const float4*)np)[q];
                t0[q*4+0] = (f16)(a.x + b.x); t0[q*4+1] = (f16)(a.y + b.y);
                t0[q*4+2] = (f16)(a.z + b.z); t0[q*4+3] = (f16)(a.w + b.w);
            }
            #pragma unroll
            for (int q = 0; q < 2; ++q) {
                float4 a = ((const float4*)xp)[q+2];
                float4 b = ((const float4*)np)[q+2];
                t1[q*4+0] = (f16)(a.x + b.x); t1[q*4+1] = (f16)(a.y + b.y);
                t1[q*4+2] = (f16)(a.z + b.z); t1[q*4+3] = (f16)(a.w + b.w);
            }
            *(f16x8*)&As[srow*40 + sk]     = t0;
            *(f16x8*)&As[srow*40 + sk + 8] = t1;
            const float* wp = W + (size_t)(colBase + srow) * I_DIM + kt + sk;
            #pragma unroll
            for (int q = 0; q < 2; ++q) {
                float4 a = ((const float4*)wp)[q];
                t0[q*4+0] = (f16)a.x; t0[q*4+1] = (f16)a.y; t0[q*4+2] = (f16)a.z; t0[q*4+3] = (f16)a.w;
            }
            #pragma unroll
            for (int q = 0; q < 2; ++q) {
                float4 a = ((const float4*)wp)[q+2];
                t1[q*4+0] = (f16)a.x; t1[q*4+1] = (f16)a.y; t1[q*4+2] = (f16)a.z; t1[q*4+3] = (f16)a.w;
            }
            *(f16x8*)&Bs[srow*40 + sk]     = t0;
            *(f16x8*)&Bs[srow*40 + sk + 8] = t1;
        }
        __syncthreads();
        f16x8 af[4], bf[4];
        #pragma unroll
        for (int i = 0; i < 4; ++i)
            af[i] = *(const f16x8*)&As[(wm*64 + i*16 + (lane & 15))*40 + ((lane >> 4) * 8)];
        #pragma unroll
        for (int i = 0; i < 4; ++i)
            bf[i] = *(const f16x8*)&Bs[(wn*64 + i*16 + (lane & 15))*40 + ((lane >> 4) * 8)];
        #pragma unroll
        for (int i = 0; i < 4; ++i)
            #pragma unroll
            for (int j = 0; j < 4; ++j)
                acc[i][j] = __builtin_amdgcn_mfma_f32_16x16x32_f16(af[i], bf[j], acc[i][j], 0, 0, 0);
        __syncthreads();
    }
    #pragma unroll
    for (int i = 0; i < 4; ++i) {
        const int row = rowBase + wm*64 + i*16 + ((lane >> 4) * 4);
        #pragma unroll
        for (int j = 0; j < 4; ++j) {
            const int col = colBase + wn*64 + j*16 + (lane & 15);
            #pragma unroll
            for (int r = 0; r < 4; ++r)
                G[(size_t)(row + r) * H_DIM + col] = (f16)acc[i][j][r];
        }
    }
}

// ---------------- output GEMM: out = Hs @ Wout^T + bout (fp32 out) ----------------
__global__ __launch_bounds__(256) void k_out_gemm(
    const f16* __restrict__ Hs, const float* __restrict__ Wout,
    const float* __restrict__ bout, float* __restrict__ out)
{
    __shared__ f16 As[128 * 40];
    __shared__ f16 Bs[128 * 40];

    const int t = threadIdx.x;
    const int lane = t & 63;
    const int w  = t >> 6;
    const int wm = w & 1, wn = w >> 1;
    const int rowBase = blockIdx.x * 128;
    const int colBase = blockIdx.y * 128;

    const int srow = t >> 1;
    const int sk   = (t & 1) * 16;

    f32x4 acc[4][4] = {};

    for (int kt = 0; kt < H_DIM; kt += 32) {
        {
            const f16* ap = Hs + (size_t)(rowBase + srow) * H_DIM + kt + sk;
            *(f16x8*)&As[srow*40 + sk]     = *(const f16x8*)ap;
            *(f16x8*)&As[srow*40 + sk + 8] = *(const f16x8*)(ap + 8);
            const float* wp = Wout + (size_t)(colBase + srow) * H_DIM + kt + sk;
            f16x8 t0, t1;
            #pragma unroll
            for (int q = 0; q < 2; ++q) {
                float4 a = ((const float4*)wp)[q];
                t0[q*4+0] = (f16)a.x; t0[q*4+1] = (f16)a.y; t0[q*4+2] = (f16)a.z; t0[q*4+3] = (f16)a.w;
            }
            #pragma unroll
            for (int q = 0; q < 2; ++q) {
                float4 a = ((const float4*)wp)[q+2];
                t1[q*4+0] = (f16)a.x; t1[q*4+1] = (f16)a.y; t1[q*4+2] = (f16)a.z; t1[q*4+3] = (f16)a.w;
            }
            *(f16x8*)&Bs[srow*40 + sk]     = t0;
            *(f16x8*)&Bs[srow*40 + sk + 8] = t1;
        }
        __syncthreads();
        f16x8 af[4], bf[4];
        #pragma unroll
        for (int i = 0; i < 4; ++i)
            af[i] = *(const f16x8*)&As[(wm*64 + i*16 + (lane & 15))*40 + ((lane >> 4) * 8)];
        #pragma unroll
        for (int i = 0; i < 4; ++i)
            bf[i] = *(const f16x8*)&Bs[(wn*64 + i*16 + (lane & 15))*40 + ((lane >> 4) * 8)];
        #pragma unroll
        for (int i = 0; i < 4; ++i)
            #pragma unroll
            for (int j = 0; j < 4; ++j)
                acc[i][j] = __builtin_amdgcn_mfma_f32_16x16x32_f16(af[i], bf[j], acc[i][j], 0, 0, 0);
        __syncthreads();
    }
    #pragma unroll
    for (int i = 0; i < 4; ++i) {
        const int row = rowBase + wm*64 + i*16 + ((lane >> 4) * 4);
        #pragma unroll
        for (int j = 0; j < 4; ++j) {
            const int col = colBase + wn*64 + j*16 + (lane & 15);
            const float bb = bout[col];
            #pragma unroll
            for (int r = 0; r < 4; ++r)
                out[(size_t)(row + r) * O_DIM + col] = acc[i][j][r] + bb;
        }
    }
}

// ---------------- persistent recurrent kernel ----------------
// R10 structure; only change: gate loads for the NEXT phase are issued
// immediately BEFORE each exchange store, so wpub's vmcnt(0) drains the
// store-ack in parallel with a useful load (ack latency hidden) and the
// next phase starts with its gate already in registers.
__global__ __launch_bounds__(512, 1) void k_recurrent(
    const f16* __restrict__ GR, const f16* __restrict__ GZ, const f16* __restrict__ GH,
    const float* __restrict__ WhR, const float* __restrict__ WhZ, const float* __restrict__ WhH,
    const float* __restrict__ bR, const float* __restrict__ bZ, const float* __restrict__ bH,
    f16* __restrict__ Rh_all, f16* __restrict__ Hs, unsigned* flg)
{
    __shared__ f16 WA[16 * 1032];   // WhR slice
    __shared__ f16 WB[16 * 1032];   // WhZ slice
    __shared__ f16 WC[16 * 1032];   // WhH slice

    unsigned* agg = flg + 8 * NWG * 16;

    const int t = threadIdx.x;
    const int lane = t & 63;
    const int w = t >> 6;
    const int wg = blockIdx.x;
    const int col0 = wg * 16;

    for (int i = t; i < 4096; i += 512) {
        int jj = i >> 8;
        int kk = (i & 255) << 2;
        float4 v = *(const float4*)(WhR + (size_t)(col0 + jj) * H_DIM + kk);
        f16x4 tv; tv[0] = (f16)v.x; tv[1] = (f16)v.y; tv[2] = (f16)v.z; tv[3] = (f16)v.w;
        *(f16x4*)&WA[jj * 1032 + kk] = tv;
        v = *(const float4*)(WhZ + (size_t)(col0 + jj) * H_DIM + kk);
        tv[0] = (f16)v.x; tv[1] = (f16)v.y; tv[2] = (f16)v.z; tv[3] = (f16)v.w;
        *(f16x4*)&WB[jj * 1032 + kk] = tv;
        v = *(const float4*)(WhH + (size_t)(col0 + jj) * H_DIM + kk);
        tv[0] = (f16)v.x; tv[1] = (f16)v.y; tv[2] = (f16)v.z; tv[3] = (f16)v.w;
        *(f16x4*)&WC[jj * 1032 + kk] = tv;
    }
    __syncthreads();   // one-time: weights staged; waves never sync again

    const int brow = w * 16 + (lane & 15);   // batch row (B-col / D-col)
    const int arow = lane & 15;              // A-row into weight LDS
    const int kcol = (lane >> 4) * 8;        // k sub-offset (halves)
    const int ocl  = (lane >> 4) * 4;        // out-col offset (D-rows)

    const f32x4 bbr = *(const f32x4*)&bR[col0 + ocl];
    const f32x4 bbz = *(const f32x4*)&bZ[col0 + ocl];
    const f32x4 bbh = *(const f32x4*)&bH[col0 + ocl];

    const size_t eoff = (size_t)brow * H_DIM + col0 + ocl;
    const size_t koff = (size_t)brow * H_DIM + kcol;

#define CONS_RZ(B, VM)                                                           \
    asm volatile("s_waitcnt vmcnt(" #VM ")" ::: "memory");                       \
    __builtin_amdgcn_sched_barrier(0);                                           \
    _Pragma("unroll")                                                            \
    for (int i = 0; i < 8; ++i) {                                                \
        const int kk = (B) * 8 + i;                                              \
        f16x8 ar = *(const f16x8*)&WA[arow * 1032 + kk * 32 + kcol];             \
        f16x8 az = *(const f16x8*)&WB[arow * 1032 + kk * 32 + kcol];             \
        accR = __builtin_amdgcn_mfma_f32_16x16x32_f16(ar, fr[kk], accR, 0, 0, 0);\
        accZ = __builtin_amdgcn_mfma_f32_16x16x32_f16(az, fr[kk], accZ, 0, 0, 0);\
    }

#define CONS_H(B, VM)                                                            \
    asm volatile("s_waitcnt vmcnt(" #VM ")" ::: "memory");                       \
    __builtin_amdgcn_sched_barrier(0);                                           \
    _Pragma("unroll")                                                            \
    for (int i = 0; i < 8; ++i) {                                                \
        const int kk = (B) * 8 + i;                                              \
        f16x8 ah = *(const f16x8*)&WC[arow * 1032 + kk * 32 + kcol];             \
        accH = __builtin_amdgcn_mfma_f32_16x16x32_f16(ah, fr[kk], accH, 0, 0, 0);\
    }

    float h32r[4] = {0.f, 0.f, 0.f, 0.f};

    // step-0 gate prefetch (R/Z)
    f16x4 gr4 = *(const f16x4*)&GR[eoff];
    f16x4 gz4 = *(const f16x4*)&GZ[eoff];

    #pragma unroll 1
    for (int step = 0; step < T_STEPS; ++step) {
        const size_t sBH = (size_t)step * BH;
        // ---- phase 1: R and Z (gr4/gz4 already in registers) ----
        f32x4 accR = {}, accZ = {};
        if (step > 0) {
            wpoll(flg, agg, w, wg, 2u * (unsigned)step, lane);   // wait h(step-1)
            const f16* hb = Hs + (sBH - BH) + koff;
            f16x8 fr[32];
            Iss<0>::go(fr, hb);
            CONS_RZ(0, 24) CONS_RZ(1, 16) CONS_RZ(2, 8) CONS_RZ(3, 0)
        }
        float zr[4];
        f16x4 rhv;
        #pragma unroll
        for (int j = 0; j < 4; ++j) {
            float pr = accR[j] + (float)gr4[j] + bbr[j];
            float rr = 1.f / (1.f + __expf(-pr));
            rhv[j] = (f16)(rr * h32r[j]);
            float pz = accZ[j] + (float)gz4[j] + bbz[j];
            zr[j] = 1.f / (1.f + __expf(-pz));
        }
        // prefetch phase-2 gate, THEN store: wpub's vmcnt(0) overlaps
        // the store-ack with this load's latency
        f16x4 gh4 = *(const f16x4*)&GH[sBH + eoff];
        gstore8_cc(Rh_all + sBH + eoff, rhv);
        wpub(flg, w, wg, 2u * (unsigned)step + 1u, lane);

        // ---- phase 2: Hhat + h update (gh4 already drained) ----
        f32x4 accH = {};
        wpoll(flg, agg, w, wg, 2u * (unsigned)step + 1u, lane);  // wait Rh(step)
        {
            const f16* rb = Rh_all + sBH + koff;
            f16x8 fr[32];
            Iss<0>::go(fr, rb);
            CONS_H(0, 24) CONS_H(1, 16) CONS_H(2, 8) CONS_H(3, 0)
        }
        f16x4 hv;
        #pragma unroll
        for (int j = 0; j < 4; ++j) {
            float ph = accH[j] + (float)gh4[j] + bbh[j];
            float e = __expf(2.f * ph);
            float th = 1.f - 2.f / (e + 1.f);
            float hn = zr[j] * h32r[j] + (1.f - zr[j]) * th;
            h32r[j] = hn;
            hv[j] = (f16)hn;
        }
        // prefetch next step's R/Z gates, THEN store h: ack hidden again
        if (step < T_STEPS - 1) {
            gr4 = *(const f16x4*)&GR[sBH + BH + eoff];
            gz4 = *(const f16x4*)&GZ[sBH + BH + eoff];
        }
        gstore8_cc(Hs + sBH + eoff, hv);
        if (step < T_STEPS - 1) wpub(flg, w, wg, 2u * (unsigned)step + 2u, lane);
    }
    asm volatile("s_waitcnt vmcnt(0)" ::: "memory");
#undef CONS_RZ
#undef CONS_H
}

extern "C" void kernel_launch(void* const* d_in, const int* in_sizes, int n_in,
                              void* d_out, int out_size, void* d_ws, size_t ws_size,
                              hipStream_t stream) {
    const float* x    = (const float*)d_in[0];
    const float* rn   = (const float*)d_in[1];
    const float* zn   = (const float*)d_in[2];
    const float* hn   = (const float*)d_in[3];
    const float* Wxz  = (const float*)d_in[4];
    const float* Wxr  = (const float*)d_in[5];
    const float* Wxh  = (const float*)d_in[6];
    const float* Whz  = (const float*)d_in[7];
    const float* bz   = (const float*)d_in[8];
    const float* Whr  = (const float*)d_in[9];
    const float* br   = (const float*)d_in[10];
    const float* Whh  = (const float*)d_in[11];
    const float* bh   = (const float*)d_in[12];
    const float* Wout = (const float*)d_in[13];
    const float* bout = (const float*)d_in[14];
    float* out = (float*)d_out;

    char* ws = (char*)d_ws;
    size_t off = 0;
    f16* GR     = (f16*)(ws + off); off += (size_t)TBROWS * H_DIM * 2;  // 64 MB
    f16* GZ     = (f16*)(ws + off); off += (size_t)TBROWS * H_DIM * 2;
    f16* GH     = (f16*)(ws + off); off += (size_t)TBROWS * H_DIM * 2;
    f16* Hs     = (f16*)(ws + off); off += (size_t)TBROWS * H_DIM * 2;
    f16* Rh_all = (f16*)(ws + off); off += (size_t)TBROWS * H_DIM * 2;
    unsigned* flg = (unsigned*)(ws + off); off += (8 * NWG + 8) * 16 * 4;

    k_init<<<1, 256, 0, stream>>>(flg);
    k_gate_gemm<<<dim3(TBROWS / 128, H_DIM / 128, 3), 256, 0, stream>>>(
        x, rn, zn, hn, Wxr, Wxz, Wxh, GR, GZ, GH);
    k_recurrent<<<NWG, 512, 0, stream>>>(
        GR, GZ, GH, Whr, Whz, Whh, br, bz, bh, Rh_all, Hs, flg);
    k_out_gemm<<<dim3(TBROWS / 128, O_DIM / 128), 256, 0, stream>>>(Hs, Wout, bout, out);
}

// Round 12
// 5590.918 us; speedup vs baseline: 1.0096x; 1.0096x over previous
//
#include <hip/hip_runtime.h>

typedef _Float16 f16;
typedef _Float16 f16x8 __attribute__((ext_vector_type(8)));
typedef _Float16 f16x4 __attribute__((ext_vector_type(4)));
typedef float    f32x4 __attribute__((ext_vector_type(4)));

#define T_STEPS 256
#define B_ROWS  128
#define I_DIM   1024
#define H_DIM   1024
#define O_DIM   512
#define TBROWS  (T_STEPS * B_ROWS)   // 32768
#define BH      (B_ROWS * H_DIM)     // 131072
#define NWG     64

// ---------------- init: zero flag + agg arrays (REQUIRED each launch:
// 0xAA poison would compare >= gen and fake-pass the polls) ----------------
__global__ void k_init(unsigned* flg) {
    for (int i = threadIdx.x; i < (8 * NWG + 8) * 16; i += 256) flg[i] = 0u;
}

// ---------- cached load (L1+L2). Safe: every handoff address is
// first-touched AFTER its producer's MALL write (step-indexed buffers,
// dispatch-start acquire invalidated all L2s; prior-replay stale lines
// hold the same deterministic values). ----------
template<int K>
__device__ __forceinline__ f16x8 gload(const f16* p) {
    f16x8 r;
    asm volatile("global_load_dwordx4 %0, %1, off offset:%c2"
                 : "=v"(r) : "v"(p), "n"(K * 64));
    return r;
}
template<int K> struct Iss {
    static __device__ __forceinline__ void go(f16x8* fr, const f16* p) {
        fr[K] = gload<K>(p);
        Iss<K + 1>::go(fr, p);
    }
};
template<> struct Iss<32> {
    static __device__ __forceinline__ void go(f16x8*, const f16*) {}
};
// write-through to MALL (cross-XCD visible; no write-back false sharing)
__device__ __forceinline__ void gstore8_cc(f16* p, f16x4 v) {
    asm volatile("global_store_dwordx2 %0, %1, off sc0 sc1"
                 :: "v"(p), "v"(v) : "memory");
}

// ---------- hierarchical per-row-group wave barrier ----------
// Publish: own-wave vmcnt(0), lane0 writes flag[w][wg] (64B-padded line,
// no store contention).
// Wait: aggregator wave (wg == grp) scans the 64 producer flags and
// publishes one combined flag agg[grp]; the other 63 waves of the group
// poll ONLY agg[grp] (single line, ~1 request/iter).
__device__ __forceinline__ void wpub(unsigned* flg, int grp, int wg, unsigned gen, int lane) {
    asm volatile("s_waitcnt vmcnt(0) lgkmcnt(0)" ::: "memory");
    if (lane == 0)
        __hip_atomic_store(&flg[(grp * NWG + wg) * 16], gen, __ATOMIC_RELAXED, __HIP_MEMORY_SCOPE_AGENT);
    __builtin_amdgcn_sched_barrier(0);
}
__device__ __forceinline__ void wpoll(unsigned* flg, unsigned* agg, int grp, int wg, unsigned gen, int lane) {
    if (wg == grp) {
        // aggregator: divergent per-lane spin over the 64 producer flags
        while (__hip_atomic_load(&flg[(grp * NWG + lane) * 16], __ATOMIC_RELAXED, __HIP_MEMORY_SCOPE_AGENT) < gen)
            __builtin_amdgcn_s_sleep(1);
        if (lane < 2)
            __hip_atomic_store(&agg[grp * 16 + lane], gen, __ATOMIC_RELAXED, __HIP_MEMORY_SCOPE_AGENT);
    } else {
        // consumers: poll the combined flag only (lane&1 keeps the address
        // lane-variant so the atomic load stays a VMEM op)
        while (__hip_atomic_load(&agg[grp * 16 + (lane & 1)], __ATOMIC_RELAXED, __HIP_MEMORY_SCOPE_AGENT) < gen)
            __builtin_amdgcn_s_sleep(1);
    }
    __builtin_amdgcn_sched_barrier(0);
}

// ---------------- gate GEMM: G_g = (x + noise_g) @ Wx_g^T  (fp16 out) ----------------
__global__ __launch_bounds__(256) void k_gate_gemm(
    const float* __restrict__ x,
    const float* __restrict__ nR, const float* __restrict__ nZ, const float* __restrict__ nH,
    const float* __restrict__ WxR, const float* __restrict__ WxZ, const float* __restrict__ WxH,
    f16* __restrict__ GR, f16* __restrict__ GZ, f16* __restrict__ GH)
{
    const int g = blockIdx.z;
    const float* noise = (g == 0) ? nR : (g == 1) ? nZ : nH;
    const float* W     = (g == 0) ? WxR : (g == 1) ? WxZ : WxH;
    f16* G             = (g == 0) ? GR : (g == 1) ? GZ : GH;

    __shared__ f16 As[128 * 40];
    __shared__ f16 Bs[128 * 40];

    const int t = threadIdx.x;
    const int lane = t & 63;
    const int w  = t >> 6;
    const int wm = w & 1, wn = w >> 1;
    const int rowBase = blockIdx.x * 128;
    const int colBase = blockIdx.y * 128;

    const int srow = t >> 1;
    const int sk   = (t & 1) * 16;

    f32x4 acc[4][4] = {};

    for (int kt = 0; kt < I_DIM; kt += 32) {
        {
            const float* xp = x     + (size_t)(rowBase + srow) * I_DIM + kt + sk;
            const float* np = noise + (size_t)(rowBase + srow) * I_DIM + kt + sk;
            f16x8 t0, t1;
            #pragma unroll
            for (int q = 0; q < 2; ++q) {
                float4 a = ((const float4*)xp)[q];
                float4 b = ((const float4*)np)[q];
                t0[q*4+0] = (f16)(a.x + b.x); t0[q*4+1] = (f16)(a.y + b.y);
                t0[q*4+2] = (f16)(a.z + b.z); t0[q*4+3] = (f16)(a.w + b.w);
            }
            #pragma unroll
            for (int q = 0; q < 2; ++q) {
                float4 a = ((const float4*)xp)[q+2];
                float4 b = ((const float4*)np)[q+2];
                t1[q*4+0] = (f16)(a.x + b.x); t1[q*4+1] = (f16)(a.y + b.y);
                t1[q*4+2] = (f16)(a.z + b.z); t1[q*4+3] = (f16)(a.w + b.w);
            }
            *(f16x8*)&As[srow*40 + sk]     = t0;
            *(f16x8*)&As[srow*40 + sk + 8] = t1;
            const float* wp = W + (size_t)(colBase + srow) * I_DIM + kt + sk;
            #pragma unroll
            for (int q = 0; q < 2; ++q) {
                float4 a = ((const float4*)wp)[q];
                t0[q*4+0] = (f16)a.x; t0[q*4+1] = (f16)a.y; t0[q*4+2] = (f16)a.z; t0[q*4+3] = (f16)a.w;
            }
            #pragma unroll
            for (int q = 0; q < 2; ++q) {
                float4 a = ((const float4*)wp)[q+2];
                t1[q*4+0] = (f16)a.x; t1[q*4+1] = (f16)a.y; t1[q*4+2] = (f16)a.z; t1[q*4+3] = (f16)a.w;
            }
            *(f16x8*)&Bs[srow*40 + sk]     = t0;
            *(f16x8*)&Bs[srow*40 + sk + 8] = t1;
        }
        __syncthreads();
        f16x8 af[4], bf[4];
        #pragma unroll
        for (int i = 0; i < 4; ++i)
            af[i] = *(const f16x8*)&As[(wm*64 + i*16 + (lane & 15))*40 + ((lane >> 4) * 8)];
        #pragma unroll
        for (int i = 0; i < 4; ++i)
            bf[i] = *(const f16x8*)&Bs[(wn*64 + i*16 + (lane & 15))*40 + ((lane >> 4) * 8)];
        #pragma unroll
        for (int i = 0; i < 4; ++i)
            #pragma unroll
            for (int j = 0; j < 4; ++j)
                acc[i][j] = __builtin_amdgcn_mfma_f32_16x16x32_f16(af[i], bf[j], acc[i][j], 0, 0, 0);
        __syncthreads();
    }
    #pragma unroll
    for (int i = 0; i < 4; ++i) {
        const int row = rowBase + wm*64 + i*16 + ((lane >> 4) * 4);
        #pragma unroll
        for (int j = 0; j < 4; ++j) {
            const int col = colBase + wn*64 + j*16 + (lane & 15);
            #pragma unroll
            for (int r = 0; r < 4; ++r)
                G[(size_t)(row + r) * H_DIM + col] = (f16)acc[i][j][r];
        }
    }
}

// ---------------- output GEMM: out = Hs @ Wout^T + bout (fp32 out) ----------------
__global__ __launch_bounds__(256) void k_out_gemm(
    const f16* __restrict__ Hs, const float* __restrict__ Wout,
    const float* __restrict__ bout, float* __restrict__ out)
{
    __shared__ f16 As[128 * 40];
    __shared__ f16 Bs[128 * 40];

    const int t = threadIdx.x;
    const int lane = t & 63;
    const int w  = t >> 6;
    const int wm = w & 1, wn = w >> 1;
    const int rowBase = blockIdx.x * 128;
    const int colBase = blockIdx.y * 128;

    const int srow = t >> 1;
    const int sk   = (t & 1) * 16;

    f32x4 acc[4][4] = {};

    for (int kt = 0; kt < H_DIM; kt += 32) {
        {
            const f16* ap = Hs + (size_t)(rowBase + srow) * H_DIM + kt + sk;
            *(f16x8*)&As[srow*40 + sk]     = *(const f16x8*)ap;
            *(f16x8*)&As[srow*40 + sk + 8] = *(const f16x8*)(ap + 8);
            const float* wp = Wout + (size_t)(colBase + srow) * H_DIM + kt + sk;
            f16x8 t0, t1;
            #pragma unroll
            for (int q = 0; q < 2; ++q) {
                float4 a = ((const float4*)wp)[q];
                t0[q*4+0] = (f16)a.x; t0[q*4+1] = (f16)a.y; t0[q*4+2] = (f16)a.z; t0[q*4+3] = (f16)a.w;
            }
            #pragma unroll
            for (int q = 0; q < 2; ++q) {
                float4 a = ((const float4*)wp)[q+2];
                t1[q*4+0] = (f16)a.x; t1[q*4+1] = (f16)a.y; t1[q*4+2] = (f16)a.z; t1[q*4+3] = (f16)a.w;
            }
            *(f16x8*)&Bs[srow*40 + sk]     = t0;
            *(f16x8*)&Bs[srow*40 + sk + 8] = t1;
        }
        __syncthreads();
        f16x8 af[4], bf[4];
        #pragma unroll
        for (int i = 0; i < 4; ++i)
            af[i] = *(const f16x8*)&As[(wm*64 + i*16 + (lane & 15))*40 + ((lane >> 4) * 8)];
        #pragma unroll
        for (int i = 0; i < 4; ++i)
            bf[i] = *(const f16x8*)&Bs[(wn*64 + i*16 + (lane & 15))*40 + ((lane >> 4) * 8)];
        #pragma unroll
        for (int i = 0; i < 4; ++i)
            #pragma unroll
            for (int j = 0; j < 4; ++j)
                acc[i][j] = __builtin_amdgcn_mfma_f32_16x16x32_f16(af[i], bf[j], acc[i][j], 0, 0, 0);
        __syncthreads();
    }
    #pragma unroll
    for (int i = 0; i < 4; ++i) {
        const int row = rowBase + wm*64 + i*16 + ((lane >> 4) * 4);
        #pragma unroll
        for (int j = 0; j < 4; ++j) {
            const int col = colBase + wn*64 + j*16 + (lane & 15);
            const float bb = bout[col];
            #pragma unroll
            for (int r = 0; r < 4; ++r)
                out[(size_t)(row + r) * O_DIM + col] = acc[i][j][r] + bb;
        }
    }
}

// ---------------- persistent recurrent kernel ----------------
// 64 WGs x 512 thr (8 waves). Wave w of WG g: batch rows 16w..+16, hidden
// cols 16g..+16. 8 independent row-group chains, each synced by its own
// hierarchical flag group (aggregator wave = wave w of WG w). Z and fp32
// h-state live in registers. Handoff: Rh_all[step] / Hs[step] written
// sc0sc1 (MALL), read with plain cached loads (step-indexed =>
// first-touch-after-write coherent). Gate loads issued before the poll
// so their latency hides under the wait.
__global__ __launch_bounds__(512, 1) void k_recurrent(
    const f16* __restrict__ GR, const f16* __restrict__ GZ, const f16* __restrict__ GH,
    const float* __restrict__ WhR, const float* __restrict__ WhZ, const float* __restrict__ WhH,
    const float* __restrict__ bR, const float* __restrict__ bZ, const float* __restrict__ bH,
    f16* __restrict__ Rh_all, f16* __restrict__ Hs, unsigned* flg)
{
    __shared__ f16 WA[16 * 1032];   // WhR slice
    __shared__ f16 WB[16 * 1032];   // WhZ slice
    __shared__ f16 WC[16 * 1032];   // WhH slice

    unsigned* agg = flg + 8 * NWG * 16;

    const int t = threadIdx.x;
    const int lane = t & 63;
    const int w = t >> 6;
    const int wg = blockIdx.x;
    const int col0 = wg * 16;

    for (int i = t; i < 4096; i += 512) {
        int jj = i >> 8;
        int kk = (i & 255) << 2;
        float4 v = *(const float4*)(WhR + (size_t)(col0 + jj) * H_DIM + kk);
        f16x4 tv; tv[0] = (f16)v.x; tv[1] = (f16)v.y; tv[2] = (f16)v.z; tv[3] = (f16)v.w;
        *(f16x4*)&WA[jj * 1032 + kk] = tv;
        v = *(const float4*)(WhZ + (size_t)(col0 + jj) * H_DIM + kk);
        tv[0] = (f16)v.x; tv[1] = (f16)v.y; tv[2] = (f16)v.z; tv[3] = (f16)v.w;
        *(f16x4*)&WB[jj * 1032 + kk] = tv;
        v = *(const float4*)(WhH + (size_t)(col0 + jj) * H_DIM + kk);
        tv[0] = (f16)v.x; tv[1] = (f16)v.y; tv[2] = (f16)v.z; tv[3] = (f16)v.w;
        *(f16x4*)&WC[jj * 1032 + kk] = tv;
    }
    __syncthreads();   // one-time: weights staged; waves never sync again

    const int brow = w * 16 + (lane & 15);   // batch row (B-col / D-col)
    const int arow = lane & 15;              // A-row into weight LDS
    const int kcol = (lane >> 4) * 8;        // k sub-offset (halves)
    const int ocl  = (lane >> 4) * 4;        // out-col offset (D-rows)

    const f32x4 bbr = *(const f32x4*)&bR[col0 + ocl];
    const f32x4 bbz = *(const f32x4*)&bZ[col0 + ocl];
    const f32x4 bbh = *(const f32x4*)&bH[col0 + ocl];

    const size_t eoff = (size_t)brow * H_DIM + col0 + ocl;
    const size_t koff = (size_t)brow * H_DIM + kcol;

#define CONS_RZ(B, VM)                                                           \
    asm volatile("s_waitcnt vmcnt(" #VM ")" ::: "memory");                       \
    __builtin_amdgcn_sched_barrier(0);                                           \
    _Pragma("unroll")                                                            \
    for (int i = 0; i < 8; ++i) {                                                \
        const int kk = (B) * 8 + i;                                              \
        f16x8 ar = *(const f16x8*)&WA[arow * 1032 + kk * 32 + kcol];             \
        f16x8 az = *(const f16x8*)&WB[arow * 1032 + kk * 32 + kcol];             \
        accR = __builtin_amdgcn_mfma_f32_16x16x32_f16(ar, fr[kk], accR, 0, 0, 0);\
        accZ = __builtin_amdgcn_mfma_f32_16x16x32_f16(az, fr[kk], accZ, 0, 0, 0);\
    }

#define CONS_H(B, VM)                                                            \
    asm volatile("s_waitcnt vmcnt(" #VM ")" ::: "memory");                       \
    __builtin_amdgcn_sched_barrier(0);                                           \
    _Pragma("unroll")                                                            \
    for (int i = 0; i < 8; ++i) {                                                \
        const int kk = (B) * 8 + i;                                              \
        f16x8 ah = *(const f16x8*)&WC[arow * 1032 + kk * 32 + kcol];             \
        accH = __builtin_amdgcn_mfma_f32_16x16x32_f16(ah, fr[kk], accH, 0, 0, 0);\
    }

    float h32r[4] = {0.f, 0.f, 0.f, 0.f};

    #pragma unroll 1
    for (int step = 0; step < T_STEPS; ++step) {
        const size_t sBH = (size_t)step * BH;
        // ---- phase 1: R and Z ----
        f32x4 accR = {}, accZ = {};
        // gate loads issued BEFORE the poll: latency hides under the wait
        f16x4 gr4 = *(const f16x4*)&GR[sBH + eoff];
        f16x4 gz4 = *(const f16x4*)&GZ[sBH + eoff];
        if (step > 0) {
            wpoll(flg, agg, w, wg, 2u * (unsigned)step, lane);   // wait h(step-1)
            const f16* hb = Hs + (sBH - BH) + koff;
            f16x8 fr[32];
            Iss<0>::go(fr, hb);
            CONS_RZ(0, 24) CONS_RZ(1, 16) CONS_RZ(2, 8) CONS_RZ(3, 0)
        }
        float zr[4];
        f16x4 rhv;
        #pragma unroll
        for (int j = 0; j < 4; ++j) {
            float pr = accR[j] + (float)gr4[j] + bbr[j];
            float rr = 1.f / (1.f + __expf(-pr));
            rhv[j] = (f16)(rr * h32r[j]);
            float pz = accZ[j] + (float)gz4[j] + bbz[j];
            zr[j] = 1.f / (1.f + __expf(-pz));
        }
        gstore8_cc(Rh_all + sBH + eoff, rhv);
        wpub(flg, w, wg, 2u * (unsigned)step + 1u, lane);

        // ---- phase 2: Hhat + h update ----
        f32x4 accH = {};
        f16x4 gh4 = *(const f16x4*)&GH[sBH + eoff];              // prefetch under poll
        wpoll(flg, agg, w, wg, 2u * (unsigned)step + 1u, lane);  // wait Rh(step)
        {
            const f16* rb = Rh_all + sBH + koff;
            f16x8 fr[32];
            Iss<0>::go(fr, rb);
            CONS_H(0, 24) CONS_H(1, 16) CONS_H(2, 8) CONS_H(3, 0)
        }
        f16x4 hv;
        #pragma unroll
        for (int j = 0; j < 4; ++j) {
            float ph = accH[j] + (float)gh4[j] + bbh[j];
            float e = __expf(2.f * ph);
            float th = 1.f - 2.f / (e + 1.f);
            float hn = zr[j] * h32r[j] + (1.f - zr[j]) * th;
            h32r[j] = hn;
            hv[j] = (f16)hn;
        }
        gstore8_cc(Hs + sBH + eoff, hv);
        if (step < T_STEPS - 1) wpub(flg, w, wg, 2u * (unsigned)step + 2u, lane);
    }
    asm volatile("s_waitcnt vmcnt(0)" ::: "memory");
#undef CONS_RZ
#undef CONS_H
}

extern "C" void kernel_launch(void* const* d_in, const int* in_sizes, int n_in,
                              void* d_out, int out_size, void* d_ws, size_t ws_size,
                              hipStream_t stream) {
    const float* x    = (const float*)d_in[0];
    const float* rn   = (const float*)d_in[1];
    const float* zn   = (const float*)d_in[2];
    const float* hn   = (const float*)d_in[3];
    const float* Wxz  = (const float*)d_in[4];
    const float* Wxr  = (const float*)d_in[5];
    const float* Wxh  = (const float*)d_in[6];
    const float* Whz  = (const float*)d_in[7];
    const float* bz   = (const float*)d_in[8];
    const float* Whr  = (const float*)d_in[9];
    const float* br   = (const float*)d_in[10];
    const float* Whh  = (const float*)d_in[11];
    const float* bh   = (const float*)d_in[12];
    const float* Wout = (const float*)d_in[13];
    const float* bout = (const float*)d_in[14];
    float* out = (float*)d_out;

    char* ws = (char*)d_ws;
    size_t off = 0;
    f16* GR     = (f16*)(ws + off); off += (size_t)TBROWS * H_DIM * 2;  // 64 MB
    f16* GZ     = (f16*)(ws + off); off += (size_t)TBROWS * H_DIM * 2;
    f16* GH     = (f16*)(ws + off); off += (size_t)TBROWS * H_DIM * 2;
    f16* Hs     = (f16*)(ws + off); off += (size_t)TBROWS * H_DIM * 2;
    f16* Rh_all = (f16*)(ws + off); off += (size_t)TBROWS * H_DIM * 2;
    unsigned* flg = (unsigned*)(ws + off); off += (8 * NWG + 8) * 16 * 4;

    k_init<<<1, 256, 0, stream>>>(flg);
    k_gate_gemm<<<dim3(TBROWS / 128, H_DIM / 128, 3), 256, 0, stream>>>(
        x, rn, zn, hn, Wxr, Wxz, Wxh, GR, GZ, GH);
    k_recurrent<<<NWG, 512, 0, stream>>>(
        GR, GZ, GH, Whr, Whz, Whh, br, bz, bh, Rh_all, Hs, flg);
    k_out_gemm<<<dim3(TBROWS / 128, O_DIM / 128), 256, 0, stream>>>(Hs, Wout, bout, out);
}

// Round 13
// 5339.062 us; speedup vs baseline: 1.0572x; 1.0472x over previous
//
#include <hip/hip_runtime.h>

typedef _Float16 f16;
typedef _Float16 f16x8 __attribute__((ext_vector_type(8)));
typedef _Float16 f16x4 __attribute__((ext_vector_type(4)));
typedef float    f32x4 __attribute__((ext_vector_type(4)));

#define T_STEPS 256
#define B_ROWS  128
#define I_DIM   1024
#define H_DIM   1024
#define O_DIM   512
#define TBROWS  (T_STEPS * B_ROWS)   // 32768
#define BH      (B_ROWS * H_DIM)     // 131072
#define NWG     64

// ---------------- init: zero flag + agg arrays (REQUIRED each launch:
// 0xAA poison would compare >= gen and fake-pass the polls) ----------------
__global__ void k_init(unsigned* flg) {
    for (int i = threadIdx.x; i < (8 * NWG + 8) * 16; i += 256) flg[i] = 0u;
}

// ---------- cached load (L1+L2). Safe: every handoff address is
// first-touched AFTER its producer's MALL write (step-indexed buffers,
// dispatch-start acquire invalidated all L2s; prior-replay stale lines
// hold the same deterministic values). ----------
template<int K>
__device__ __forceinline__ f16x8 gload(const f16* p) {
    f16x8 r;
    asm volatile("global_load_dwordx4 %0, %1, off offset:%c2"
                 : "=v"(r) : "v"(p), "n"(K * 64));
    return r;
}
template<int K> struct Iss {
    static __device__ __forceinline__ void go(f16x8* fr, const f16* p) {
        fr[K] = gload<K>(p);
        Iss<K + 1>::go(fr, p);
    }
};
template<> struct Iss<32> {
    static __device__ __forceinline__ void go(f16x8*, const f16*) {}
};
// write-through to MALL (cross-XCD visible; no write-back false sharing)
__device__ __forceinline__ void gstore8_cc(f16* p, f16x4 v) {
    asm volatile("global_store_dwordx2 %0, %1, off sc0 sc1"
                 :: "v"(p), "v"(v) : "memory");
}

// ---------- hierarchical per-row-group wave barrier ----------
__device__ __forceinline__ void wpub(unsigned* flg, int grp, int wg, unsigned gen, int lane) {
    asm volatile("s_waitcnt vmcnt(0) lgkmcnt(0)" ::: "memory");
    if (lane == 0)
        __hip_atomic_store(&flg[(grp * NWG + wg) * 16], gen, __ATOMIC_RELAXED, __HIP_MEMORY_SCOPE_AGENT);
    __builtin_amdgcn_sched_barrier(0);
}
__device__ __forceinline__ void wpoll(unsigned* flg, unsigned* agg, int grp, int wg, unsigned gen, int lane) {
    if (wg == grp) {
        while (__hip_atomic_load(&flg[(grp * NWG + lane) * 16], __ATOMIC_RELAXED, __HIP_MEMORY_SCOPE_AGENT) < gen)
            __builtin_amdgcn_s_sleep(1);
        if (lane < 2)
            __hip_atomic_store(&agg[grp * 16 + lane], gen, __ATOMIC_RELAXED, __HIP_MEMORY_SCOPE_AGENT);
    } else {
        while (__hip_atomic_load(&agg[grp * 16 + (lane & 1)], __ATOMIC_RELAXED, __HIP_MEMORY_SCOPE_AGENT) < gen)
            __builtin_amdgcn_s_sleep(1);
    }
    __builtin_amdgcn_sched_barrier(0);
}

// ---------------- gate GEMM: G_g = (x + noise_g) @ Wx_g^T  (fp16 out) ----------------
// Flattened grid + bijective XCD-chunked swizzle: col-tile fastest WITHIN an
// XCD's contiguous row-chunk, so the 1MB A-tile (x+noise rows) is fetched
// once and L2-hits for the other 7 col-tiles; per-gate W (4MB) stays
// L2-resident across the row sweep. Cuts A-stream HBM traffic ~8x.
__global__ __launch_bounds__(256) void k_gate_gemm(
    const float* __restrict__ x,
    const float* __restrict__ nR, const float* __restrict__ nZ, const float* __restrict__ nH,
    const float* __restrict__ WxR, const float* __restrict__ WxZ, const float* __restrict__ WxH,
    f16* __restrict__ GR, f16* __restrict__ GZ, f16* __restrict__ GH)
{
    const int g = blockIdx.z;
    const float* noise = (g == 0) ? nR : (g == 1) ? nZ : nH;
    const float* W     = (g == 0) ? WxR : (g == 1) ? WxZ : WxH;
    f16* G             = (g == 0) ? GR : (g == 1) ? GZ : GH;

    __shared__ f16 As[128 * 40];
    __shared__ f16 Bs[128 * 40];

    const int t = threadIdx.x;
    const int lane = t & 63;
    const int w  = t >> 6;
    const int wm = w & 1, wn = w >> 1;
    // 2048 blocks: l = (bid%8)*256 + bid/8 (bijective); row = l>>3, col = l&7
    const int bid = blockIdx.x;
    const int l   = (bid & 7) * 256 + (bid >> 3);
    const int rowBase = (l >> 3) * 128;
    const int colBase = (l & 7) * 128;

    const int srow = t >> 1;
    const int sk   = (t & 1) * 16;

    f32x4 acc[4][4] = {};

    for (int kt = 0; kt < I_DIM; kt += 32) {
        {
            const float* xp = x     + (size_t)(rowBase + srow) * I_DIM + kt + sk;
            const float* np = noise + (size_t)(rowBase + srow) * I_DIM + kt + sk;
            f16x8 t0, t1;
            #pragma unroll
            for (int q = 0; q < 2; ++q) {
                float4 a = ((const float4*)xp)[q];
                float4 b = ((const float4*)np)[q];
                t0[q*4+0] = (f16)(a.x + b.x); t0[q*4+1] = (f16)(a.y + b.y);
                t0[q*4+2] = (f16)(a.z + b.z); t0[q*4+3] = (f16)(a.w + b.w);
            }
            #pragma unroll
            for (int q = 0; q < 2; ++q) {
                float4 a = ((const float4*)xp)[q+2];
                float4 b = ((const float4*)np)[q+2];
                t1[q*4+0] = (f16)(a.x + b.x); t1[q*4+1] = (f16)(a.y + b.y);
                t1[q*4+2] = (f16)(a.z + b.z); t1[q*4+3] = (f16)(a.w + b.w);
            }
            *(f16x8*)&As[srow*40 + sk]     = t0;
            *(f16x8*)&As[srow*40 + sk + 8] = t1;
            const float* wp = W + (size_t)(colBase + srow) * I_DIM + kt + sk;
            #pragma unroll
            for (int q = 0; q < 2; ++q) {
                float4 a = ((const float4*)wp)[q];
                t0[q*4+0] = (f16)a.x; t0[q*4+1] = (f16)a.y; t0[q*4+2] = (f16)a.z; t0[q*4+3] = (f16)a.w;
            }
            #pragma unroll
            for (int q = 0; q < 2; ++q) {
                float4 a = ((const float4*)wp)[q+2];
                t1[q*4+0] = (f16)a.x; t1[q*4+1] = (f16)a.y; t1[q*4+2] = (f16)a.z; t1[q*4+3] = (f16)a.w;
            }
            *(f16x8*)&Bs[srow*40 + sk]     = t0;
            *(f16x8*)&Bs[srow*40 + sk + 8] = t1;
        }
        __syncthreads();
        f16x8 af[4], bf[4];
        #pragma unroll
        for (int i = 0; i < 4; ++i)
            af[i] = *(const f16x8*)&As[(wm*64 + i*16 + (lane & 15))*40 + ((lane >> 4) * 8)];
        #pragma unroll
        for (int i = 0; i < 4; ++i)
            bf[i] = *(const f16x8*)&Bs[(wn*64 + i*16 + (lane & 15))*40 + ((lane >> 4) * 8)];
        #pragma unroll
        for (int i = 0; i < 4; ++i)
            #pragma unroll
            for (int j = 0; j < 4; ++j)
                acc[i][j] = __builtin_amdgcn_mfma_f32_16x16x32_f16(af[i], bf[j], acc[i][j], 0, 0, 0);
        __syncthreads();
    }
    #pragma unroll
    for (int i = 0; i < 4; ++i) {
        const int row = rowBase + wm*64 + i*16 + ((lane >> 4) * 4);
        #pragma unroll
        for (int j = 0; j < 4; ++j) {
            const int col = colBase + wn*64 + j*16 + (lane & 15);
            #pragma unroll
            for (int r = 0; r < 4; ++r)
                G[(size_t)(row + r) * H_DIM + col] = (f16)acc[i][j][r];
        }
    }
}

// ---------------- output GEMM: out = Hs @ Wout^T + bout (fp32 out) ----------------
// Same swizzle: 1024 blocks, 4 col-tiles per row consecutive on one XCD.
__global__ __launch_bounds__(256) void k_out_gemm(
    const f16* __restrict__ Hs, const float* __restrict__ Wout,
    const float* __restrict__ bout, float* __restrict__ out)
{
    __shared__ f16 As[128 * 40];
    __shared__ f16 Bs[128 * 40];

    const int t = threadIdx.x;
    const int lane = t & 63;
    const int w  = t >> 6;
    const int wm = w & 1, wn = w >> 1;
    const int bid = blockIdx.x;
    const int l   = (bid & 7) * 128 + (bid >> 3);
    const int rowBase = (l >> 2) * 128;
    const int colBase = (l & 3) * 128;

    const int srow = t >> 1;
    const int sk   = (t & 1) * 16;

    f32x4 acc[4][4] = {};

    for (int kt = 0; kt < H_DIM; kt += 32) {
        {
            const f16* ap = Hs + (size_t)(rowBase + srow) * H_DIM + kt + sk;
            *(f16x8*)&As[srow*40 + sk]     = *(const f16x8*)ap;
            *(f16x8*)&As[srow*40 + sk + 8] = *(const f16x8*)(ap + 8);
            const float* wp = Wout + (size_t)(colBase + srow) * H_DIM + kt + sk;
            f16x8 t0, t1;
            #pragma unroll
            for (int q = 0; q < 2; ++q) {
                float4 a = ((const float4*)wp)[q];
                t0[q*4+0] = (f16)a.x; t0[q*4+1] = (f16)a.y; t0[q*4+2] = (f16)a.z; t0[q*4+3] = (f16)a.w;
            }
            #pragma unroll
            for (int q = 0; q < 2; ++q) {
                float4 a = ((const float4*)wp)[q+2];
                t1[q*4+0] = (f16)a.x; t1[q*4+1] = (f16)a.y; t1[q*4+2] = (f16)a.z; t1[q*4+3] = (f16)a.w;
            }
            *(f16x8*)&Bs[srow*40 + sk]     = t0;
            *(f16x8*)&Bs[srow*40 + sk + 8] = t1;
        }
        __syncthreads();
        f16x8 af[4], bf[4];
        #pragma unroll
        for (int i = 0; i < 4; ++i)
            af[i] = *(const f16x8*)&As[(wm*64 + i*16 + (lane & 15))*40 + ((lane >> 4) * 8)];
        #pragma unroll
        for (int i = 0; i < 4; ++i)
            bf[i] = *(const f16x8*)&Bs[(wn*64 + i*16 + (lane & 15))*40 + ((lane >> 4) * 8)];
        #pragma unroll
        for (int i = 0; i < 4; ++i)
            #pragma unroll
            for (int j = 0; j < 4; ++j)
                acc[i][j] = __builtin_amdgcn_mfma_f32_16x16x32_f16(af[i], bf[j], acc[i][j], 0, 0, 0);
        __syncthreads();
    }
    #pragma unroll
    for (int i = 0; i < 4; ++i) {
        const int row = rowBase + wm*64 + i*16 + ((lane >> 4) * 4);
        #pragma unroll
        for (int j = 0; j < 4; ++j) {
            const int col = colBase + wn*64 + j*16 + (lane & 15);
            const float bb = bout[col];
            #pragma unroll
            for (int r = 0; r < 4; ++r)
                out[(size_t)(row + r) * O_DIM + col] = acc[i][j][r] + bb;
        }
    }
}

// ---------------- persistent recurrent kernel (unchanged from R10/R12) ----------------
__global__ __launch_bounds__(512, 1) void k_recurrent(
    const f16* __restrict__ GR, const f16* __restrict__ GZ, const f16* __restrict__ GH,
    const float* __restrict__ WhR, const float* __restrict__ WhZ, const float* __restrict__ WhH,
    const float* __restrict__ bR, const float* __restrict__ bZ, const float* __restrict__ bH,
    f16* __restrict__ Rh_all, f16* __restrict__ Hs, unsigned* flg)
{
    __shared__ f16 WA[16 * 1032];   // WhR slice
    __shared__ f16 WB[16 * 1032];   // WhZ slice
    __shared__ f16 WC[16 * 1032];   // WhH slice

    unsigned* agg = flg + 8 * NWG * 16;

    const int t = threadIdx.x;
    const int lane = t & 63;
    const int w = t >> 6;
    const int wg = blockIdx.x;
    const int col0 = wg * 16;

    for (int i = t; i < 4096; i += 512) {
        int jj = i >> 8;
        int kk = (i & 255) << 2;
        float4 v = *(const float4*)(WhR + (size_t)(col0 + jj) * H_DIM + kk);
        f16x4 tv; tv[0] = (f16)v.x; tv[1] = (f16)v.y; tv[2] = (f16)v.z; tv[3] = (f16)v.w;
        *(f16x4*)&WA[jj * 1032 + kk] = tv;
        v = *(const float4*)(WhZ + (size_t)(col0 + jj) * H_DIM + kk);
        tv[0] = (f16)v.x; tv[1] = (f16)v.y; tv[2] = (f16)v.z; tv[3] = (f16)v.w;
        *(f16x4*)&WB[jj * 1032 + kk] = tv;
        v = *(const float4*)(WhH + (size_t)(col0 + jj) * H_DIM + kk);
        tv[0] = (f16)v.x; tv[1] = (f16)v.y; tv[2] = (f16)v.z; tv[3] = (f16)v.w;
        *(f16x4*)&WC[jj * 1032 + kk] = tv;
    }
    __syncthreads();   // one-time: weights staged; waves never sync again

    const int brow = w * 16 + (lane & 15);   // batch row (B-col / D-col)
    const int arow = lane & 15;              // A-row into weight LDS
    const int kcol = (lane >> 4) * 8;        // k sub-offset (halves)
    const int ocl  = (lane >> 4) * 4;        // out-col offset (D-rows)

    const f32x4 bbr = *(const f32x4*)&bR[col0 + ocl];
    const f32x4 bbz = *(const f32x4*)&bZ[col0 + ocl];
    const f32x4 bbh = *(const f32x4*)&bH[col0 + ocl];

    const size_t eoff = (size_t)brow * H_DIM + col0 + ocl;
    const size_t koff = (size_t)brow * H_DIM + kcol;

#define CONS_RZ(B, VM)                                                           \
    asm volatile("s_waitcnt vmcnt(" #VM ")" ::: "memory");                       \
    __builtin_amdgcn_sched_barrier(0);                                           \
    _Pragma("unroll")                                                            \
    for (int i = 0; i < 8; ++i) {                                                \
        const int kk = (B) * 8 + i;                                              \
        f16x8 ar = *(const f16x8*)&WA[arow * 1032 + kk * 32 + kcol];             \
        f16x8 az = *(const f16x8*)&WB[arow * 1032 + kk * 32 + kcol];             \
        accR = __builtin_amdgcn_mfma_f32_16x16x32_f16(ar, fr[kk], accR, 0, 0, 0);\
        accZ = __builtin_amdgcn_mfma_f32_16x16x32_f16(az, fr[kk], accZ, 0, 0, 0);\
    }

#define CONS_H(B, VM)                                                            \
    asm volatile("s_waitcnt vmcnt(" #VM ")" ::: "memory");                       \
    __builtin_amdgcn_sched_barrier(0);                                           \
    _Pragma("unroll")                                                            \
    for (int i = 0; i < 8; ++i) {                                                \
        const int kk = (B) * 8 + i;                                              \
        f16x8 ah = *(const f16x8*)&WC[arow * 1032 + kk * 32 + kcol];             \
        accH = __builtin_amdgcn_mfma_f32_16x16x32_f16(ah, fr[kk], accH, 0, 0, 0);\
    }

    float h32r[4] = {0.f, 0.f, 0.f, 0.f};

    #pragma unroll 1
    for (int step = 0; step < T_STEPS; ++step) {
        const size_t sBH = (size_t)step * BH;
        // ---- phase 1: R and Z ----
        f32x4 accR = {}, accZ = {};
        // gate loads issued BEFORE the poll: latency hides under the wait
        f16x4 gr4 = *(const f16x4*)&GR[sBH + eoff];
        f16x4 gz4 = *(const f16x4*)&GZ[sBH + eoff];
        if (step > 0) {
            wpoll(flg, agg, w, wg, 2u * (unsigned)step, lane);   // wait h(step-1)
            const f16* hb = Hs + (sBH - BH) + koff;
            f16x8 fr[32];
            Iss<0>::go(fr, hb);
            CONS_RZ(0, 24) CONS_RZ(1, 16) CONS_RZ(2, 8) CONS_RZ(3, 0)
        }
        float zr[4];
        f16x4 rhv;
        #pragma unroll
        for (int j = 0; j < 4; ++j) {
            float pr = accR[j] + (float)gr4[j] + bbr[j];
            float rr = 1.f / (1.f + __expf(-pr));
            rhv[j] = (f16)(rr * h32r[j]);
            float pz = accZ[j] + (float)gz4[j] + bbz[j];
            zr[j] = 1.f / (1.f + __expf(-pz));
        }
        gstore8_cc(Rh_all + sBH + eoff, rhv);
        wpub(flg, w, wg, 2u * (unsigned)step + 1u, lane);

        // ---- phase 2: Hhat + h update ----
        f32x4 accH = {};
        f16x4 gh4 = *(const f16x4*)&GH[sBH + eoff];              // prefetch under poll
        wpoll(flg, agg, w, wg, 2u * (unsigned)step + 1u, lane);  // wait Rh(step)
        {
            const f16* rb = Rh_all + sBH + koff;
            f16x8 fr[32];
            Iss<0>::go(fr, rb);
            CONS_H(0, 24) CONS_H(1, 16) CONS_H(2, 8) CONS_H(3, 0)
        }
        f16x4 hv;
        #pragma unroll
        for (int j = 0; j < 4; ++j) {
            float ph = accH[j] + (float)gh4[j] + bbh[j];
            float e = __expf(2.f * ph);
            float th = 1.f - 2.f / (e + 1.f);
            float hn = zr[j] * h32r[j] + (1.f - zr[j]) * th;
            h32r[j] = hn;
            hv[j] = (f16)hn;
        }
        gstore8_cc(Hs + sBH + eoff, hv);
        if (step < T_STEPS - 1) wpub(flg, w, wg, 2u * (unsigned)step + 2u, lane);
    }
    asm volatile("s_waitcnt vmcnt(0)" ::: "memory");
#undef CONS_RZ
#undef CONS_H
}

extern "C" void kernel_launch(void* const* d_in, const int* in_sizes, int n_in,
                              void* d_out, int out_size, void* d_ws, size_t ws_size,
                              hipStream_t stream) {
    const float* x    = (const float*)d_in[0];
    const float* rn   = (const float*)d_in[1];
    const float* zn   = (const float*)d_in[2];
    const float* hn   = (const float*)d_in[3];
    const float* Wxz  = (const float*)d_in[4];
    const float* Wxr  = (const float*)d_in[5];
    const float* Wxh  = (const float*)d_in[6];
    const float* Whz  = (const float*)d_in[7];
    const float* bz   = (const float*)d_in[8];
    const float* Whr  = (const float*)d_in[9];
    const float* br   = (const float*)d_in[10];
    const float* Whh  = (const float*)d_in[11];
    const float* bh   = (const float*)d_in[12];
    const float* Wout = (const float*)d_in[13];
    const float* bout = (const float*)d_in[14];
    float* out = (float*)d_out;

    char* ws = (char*)d_ws;
    size_t off = 0;
    f16* GR     = (f16*)(ws + off); off += (size_t)TBROWS * H_DIM * 2;  // 64 MB
    f16* GZ     = (f16*)(ws + off); off += (size_t)TBROWS * H_DIM * 2;
    f16* GH     = (f16*)(ws + off); off += (size_t)TBROWS * H_DIM * 2;
    f16* Hs     = (f16*)(ws + off); off += (size_t)TBROWS * H_DIM * 2;
    f16* Rh_all = (f16*)(ws + off); off += (size_t)TBROWS * H_DIM * 2;
    unsigned* flg = (unsigned*)(ws + off); off += (8 * NWG + 8) * 16 * 4;

    k_init<<<1, 256, 0, stream>>>(flg);
    k_gate_gemm<<<dim3(2048, 1, 3), 256, 0, stream>>>(
        x, rn, zn, hn, Wxr, Wxz, Wxh, GR, GZ, GH);
    k_recurrent<<<NWG, 512, 0, stream>>>(
        GR, GZ, GH, Whr, Whz, Whh, br, bz, bh, Rh_all, Hs, flg);
    k_out_gemm<<<1024, 256, 0, stream>>>(Hs, Wout, bout, out);
}

// Round 14
// 4664.354 us; speedup vs baseline: 1.2101x; 1.1447x over previous
//
#include <hip/hip_runtime.h>

typedef _Float16 f16;
typedef _Float16 f16x8 __attribute__((ext_vector_type(8)));
typedef _Float16 f16x4 __attribute__((ext_vector_type(4)));
typedef float    f32x4 __attribute__((ext_vector_type(4)));

#define T_STEPS 256
#define B_ROWS  128
#define I_DIM   1024
#define H_DIM   1024
#define O_DIM   512
#define TBROWS  (T_STEPS * B_ROWS)   // 32768
#define BH      (B_ROWS * H_DIM)     // 131072
#define NWG     64
#define GBLK    (T_STEPS * 24)       // 6144 gate blocks (24 per step)

// ---------------- init: zero flags + agg + step counters (REQUIRED each
// launch: 0xAA poison would fake-pass the polls) ----------------
__global__ void k_init(unsigned* flg) {
    for (int i = threadIdx.x; i < (8 * NWG + 8 + 257) * 16; i += 256) flg[i] = 0u;
}

// ---------- cached load (L1+L2). Safe: every handoff address is
// first-touched AFTER its producer's MALL write; graph replays are
// deterministic so stale lines hold identical values. ----------
template<int K>
__device__ __forceinline__ f16x8 gload(const f16* p) {
    f16x8 r;
    asm volatile("global_load_dwordx4 %0, %1, off offset:%c2"
                 : "=v"(r) : "v"(p), "n"(K * 64));
    return r;
}
template<int K> struct Iss {
    static __device__ __forceinline__ void go(f16x8* fr, const f16* p) {
        fr[K] = gload<K>(p);
        Iss<K + 1>::go(fr, p);
    }
};
template<> struct Iss<32> {
    static __device__ __forceinline__ void go(f16x8*, const f16*) {}
};
// write-through to MALL (cross-XCD visible; no write-back false sharing)
__device__ __forceinline__ void gstore8_cc(f16* p, f16x4 v) {
    asm volatile("global_store_dwordx2 %0, %1, off sc0 sc1"
                 :: "v"(p), "v"(v) : "memory");
}
__device__ __forceinline__ void gstore2_cc(f16* p, f16 v) {
    union { f16 f; unsigned short s; } u; u.f = v;
    unsigned uv = u.s;
    asm volatile("global_store_short %0, %1, off sc0 sc1"
                 :: "v"(p), "v"(uv) : "memory");
}

// ---------- hierarchical per-row-group wave barrier (R10, proven) ----------
__device__ __forceinline__ void wpub(unsigned* flg, int grp, int wg, unsigned gen, int lane) {
    asm volatile("s_waitcnt vmcnt(0) lgkmcnt(0)" ::: "memory");
    if (lane == 0)
        __hip_atomic_store(&flg[(grp * NWG + wg) * 16], gen, __ATOMIC_RELAXED, __HIP_MEMORY_SCOPE_AGENT);
    __builtin_amdgcn_sched_barrier(0);
}
__device__ __forceinline__ void wpoll(unsigned* flg, unsigned* agg, int grp, int wg, unsigned gen, int lane) {
    if (wg == grp) {
        while (__hip_atomic_load(&flg[(grp * NWG + lane) * 16], __ATOMIC_RELAXED, __HIP_MEMORY_SCOPE_AGENT) < gen)
            __builtin_amdgcn_s_sleep(1);
        if (lane < 2)
            __hip_atomic_store(&agg[grp * 16 + lane], gen, __ATOMIC_RELAXED, __HIP_MEMORY_SCOPE_AGENT);
    } else {
        while (__hip_atomic_load(&agg[grp * 16 + (lane & 1)], __ATOMIC_RELAXED, __HIP_MEMORY_SCOPE_AGENT) < gen)
            __builtin_amdgcn_s_sleep(1);
    }
    __builtin_amdgcn_sched_barrier(0);
}

// ---------------- FUSED kernel: recurrence (blocks 0..63) + gate GEMM
// producers (blocks 64..). Gate blocks: 24 per step (8 col x 3 gates),
// step-major order -> early steps first. G written write-through (sc0sc1),
// per-step counter published after vmcnt(0). Recurrent polls cnt[step]==24
// (prefetched one step ahead -> steady-state free). Gate blocks never wait
// => no deadlock; worst-case dispatch = serial (today's behavior).
__global__ __launch_bounds__(512, 1) void k_fused(
    const float* __restrict__ x,
    const float* __restrict__ nR, const float* __restrict__ nZ, const float* __restrict__ nH,
    const float* __restrict__ WxR, const float* __restrict__ WxZ, const float* __restrict__ WxH,
    const float* __restrict__ WhR, const float* __restrict__ WhZ, const float* __restrict__ WhH,
    const float* __restrict__ bR, const float* __restrict__ bZ, const float* __restrict__ bH,
    f16* __restrict__ GR, f16* __restrict__ GZ, f16* __restrict__ GH,
    f16* __restrict__ Rh_all, f16* __restrict__ Hs, unsigned* flg)
{
    __shared__ __align__(16) char smem[99072];   // union: 3x16x1032 f16 | 2x128x40 f16

    unsigned* agg = flg + 8 * NWG * 16;
    unsigned* cnt = flg + (8 * NWG + 8) * 16;

    const int bid  = blockIdx.x;
    const int t    = threadIdx.x;
    const int lane = t & 63;
    const int w    = t >> 6;

    if (bid >= NWG) {
        // ================= gate-producer role =================
        const int gid  = bid - NWG;
        const int s    = gid / 24;
        const int rem  = gid - s * 24;
        const int g    = rem >> 3;
        const int colT = rem & 7;
        const float* noise = (g == 0) ? nR : (g == 1) ? nZ : nH;
        const float* W     = (g == 0) ? WxR : (g == 1) ? WxZ : WxH;
        f16* G             = (g == 0) ? GR : (g == 1) ? GZ : GH;
        const int rowBase = s * 128;
        const int colBase = colT * 128;

        f16* As = (f16*)smem;            // [128][40]
        f16* Bs = As + 128 * 40;

        const int srow = t >> 2;         // 0..127
        const int sk   = (t & 3) * 8;    // 0,8,16,24
        const int wm = w & 1, wn = w >> 1;   // 2 x 4 wave grid (64x32 per wave)

        f32x4 acc[4][2] = {};

        for (int kt = 0; kt < I_DIM; kt += 32) {
            {
                const float* xp = x     + (size_t)(rowBase + srow) * I_DIM + kt + sk;
                const float* np = noise + (size_t)(rowBase + srow) * I_DIM + kt + sk;
                f16x8 t0;
                #pragma unroll
                for (int q = 0; q < 2; ++q) {
                    float4 a = ((const float4*)xp)[q];
                    float4 b = ((const float4*)np)[q];
                    t0[q*4+0] = (f16)(a.x + b.x); t0[q*4+1] = (f16)(a.y + b.y);
                    t0[q*4+2] = (f16)(a.z + b.z); t0[q*4+3] = (f16)(a.w + b.w);
                }
                *(f16x8*)&As[srow * 40 + sk] = t0;
                const float* wp = W + (size_t)(colBase + srow) * I_DIM + kt + sk;
                #pragma unroll
                for (int q = 0; q < 2; ++q) {
                    float4 a = ((const float4*)wp)[q];
                    t0[q*4+0] = (f16)a.x; t0[q*4+1] = (f16)a.y;
                    t0[q*4+2] = (f16)a.z; t0[q*4+3] = (f16)a.w;
                }
                *(f16x8*)&Bs[srow * 40 + sk] = t0;
            }
            __syncthreads();
            f16x8 af[4], bf[2];
            #pragma unroll
            for (int i = 0; i < 4; ++i)
                af[i] = *(const f16x8*)&As[(wm*64 + i*16 + (lane & 15))*40 + ((lane >> 4) * 8)];
            #pragma unroll
            for (int j = 0; j < 2; ++j)
                bf[j] = *(const f16x8*)&Bs[(wn*32 + j*16 + (lane & 15))*40 + ((lane >> 4) * 8)];
            #pragma unroll
            for (int i = 0; i < 4; ++i)
                #pragma unroll
                for (int j = 0; j < 2; ++j)
                    acc[i][j] = __builtin_amdgcn_mfma_f32_16x16x32_f16(af[i], bf[j], acc[i][j], 0, 0, 0);
            __syncthreads();
        }
        #pragma unroll
        for (int i = 0; i < 4; ++i) {
            const int row = rowBase + wm*64 + i*16 + ((lane >> 4) * 4);
            #pragma unroll
            for (int j = 0; j < 2; ++j) {
                const int col = colBase + wn*32 + j*16 + (lane & 15);
                #pragma unroll
                for (int r = 0; r < 4; ++r)
                    gstore2_cc(&G[(size_t)(row + r) * H_DIM + col], (f16)acc[i][j][r]);
            }
        }
        asm volatile("s_waitcnt vmcnt(0)" ::: "memory");   // stores acked at MALL
        __syncthreads();
        if (t == 0)
            __hip_atomic_fetch_add(&cnt[s * 16], 1u, __ATOMIC_RELAXED, __HIP_MEMORY_SCOPE_AGENT);
        return;
    }

    // ================= recurrent role (R10 structure, unchanged core) =================
    f16* WA = (f16*)smem;
    f16* WB = WA + 16 * 1032;
    f16* WC = WB + 16 * 1032;

    const int wg = bid;
    const int col0 = wg * 16;

    for (int i = t; i < 4096; i += 512) {
        int jj = i >> 8;
        int kk = (i & 255) << 2;
        float4 v = *(const float4*)(WhR + (size_t)(col0 + jj) * H_DIM + kk);
        f16x4 tv; tv[0] = (f16)v.x; tv[1] = (f16)v.y; tv[2] = (f16)v.z; tv[3] = (f16)v.w;
        *(f16x4*)&WA[jj * 1032 + kk] = tv;
        v = *(const float4*)(WhZ + (size_t)(col0 + jj) * H_DIM + kk);
        tv[0] = (f16)v.x; tv[1] = (f16)v.y; tv[2] = (f16)v.z; tv[3] = (f16)v.w;
        *(f16x4*)&WB[jj * 1032 + kk] = tv;
        v = *(const float4*)(WhH + (size_t)(col0 + jj) * H_DIM + kk);
        tv[0] = (f16)v.x; tv[1] = (f16)v.y; tv[2] = (f16)v.z; tv[3] = (f16)v.w;
        *(f16x4*)&WC[jj * 1032 + kk] = tv;
    }
    __syncthreads();   // one-time: weights staged

    const int brow = w * 16 + (lane & 15);
    const int arow = lane & 15;
    const int kcol = (lane >> 4) * 8;
    const int ocl  = (lane >> 4) * 4;

    const f32x4 bbr = *(const f32x4*)&bR[col0 + ocl];
    const f32x4 bbz = *(const f32x4*)&bZ[col0 + ocl];
    const f32x4 bbh = *(const f32x4*)&bH[col0 + ocl];

    const size_t eoff = (size_t)brow * H_DIM + col0 + ocl;
    const size_t koff = (size_t)brow * H_DIM + kcol;

#define CONS_RZ(B, VM)                                                           \
    asm volatile("s_waitcnt vmcnt(" #VM ")" ::: "memory");                       \
    __builtin_amdgcn_sched_barrier(0);                                           \
    _Pragma("unroll")                                                            \
    for (int i = 0; i < 8; ++i) {                                                \
        const int kk = (B) * 8 + i;                                              \
        f16x8 ar = *(const f16x8*)&WA[arow * 1032 + kk * 32 + kcol];             \
        f16x8 az = *(const f16x8*)&WB[arow * 1032 + kk * 32 + kcol];             \
        accR = __builtin_amdgcn_mfma_f32_16x16x32_f16(ar, fr[kk], accR, 0, 0, 0);\
        accZ = __builtin_amdgcn_mfma_f32_16x16x32_f16(az, fr[kk], accZ, 0, 0, 0);\
    }

#define CONS_H(B, VM)                                                            \
    asm volatile("s_waitcnt vmcnt(" #VM ")" ::: "memory");                       \
    __builtin_amdgcn_sched_barrier(0);                                           \
    _Pragma("unroll")                                                            \
    for (int i = 0; i < 8; ++i) {                                                \
        const int kk = (B) * 8 + i;                                              \
        f16x8 ah = *(const f16x8*)&WC[arow * 1032 + kk * 32 + kcol];             \
        accH = __builtin_amdgcn_mfma_f32_16x16x32_f16(ah, fr[kk], accH, 0, 0, 0);\
    }

    float h32r[4] = {0.f, 0.f, 0.f, 0.f};
    unsigned cr_next = 0;   // prefetched cnt for the upcoming step

    #pragma unroll 1
    for (int step = 0; step < T_STEPS; ++step) {
        const size_t sBH = (size_t)step * BH;
        // ---- gate-ready check (prefetched; spins only during warmup) ----
        if (cr_next < 24u) {
            while (__hip_atomic_load(&cnt[step * 16], __ATOMIC_RELAXED, __HIP_MEMORY_SCOPE_AGENT) < 24u)
                __builtin_amdgcn_s_sleep(1);
        }
        __builtin_amdgcn_sched_barrier(0);

        // ---- phase 1: R and Z ----
        f32x4 accR = {}, accZ = {};
        f16x4 gr4 = *(const f16x4*)&GR[sBH + eoff];
        f16x4 gz4 = *(const f16x4*)&GZ[sBH + eoff];
        if (step > 0) {
            wpoll(flg, agg, w, wg, 2u * (unsigned)step, lane);   // wait h(step-1)
            const f16* hb = Hs + (sBH - BH) + koff;
            f16x8 fr[32];
            Iss<0>::go(fr, hb);
            CONS_RZ(0, 24) CONS_RZ(1, 16) CONS_RZ(2, 8) CONS_RZ(3, 0)
        }
        float zr[4];
        f16x4 rhv;
        #pragma unroll
        for (int j = 0; j < 4; ++j) {
            float pr = accR[j] + (float)gr4[j] + bbr[j];
            float rr = 1.f / (1.f + __expf(-pr));
            rhv[j] = (f16)(rr * h32r[j]);
            float pz = accZ[j] + (float)gz4[j] + bbz[j];
            zr[j] = 1.f / (1.f + __expf(-pz));
        }
        gstore8_cc(Rh_all + sBH + eoff, rhv);
        wpub(flg, w, wg, 2u * (unsigned)step + 1u, lane);

        // ---- phase 2: Hhat + h update ----
        f32x4 accH = {};
        f16x4 gh4 = *(const f16x4*)&GH[sBH + eoff];              // prefetch under poll
        if (step + 1 < T_STEPS)                                   // prefetch next step's readiness
            cr_next = __hip_atomic_load(&cnt[(step + 1) * 16], __ATOMIC_RELAXED, __HIP_MEMORY_SCOPE_AGENT);
        wpoll(flg, agg, w, wg, 2u * (unsigned)step + 1u, lane);  // wait Rh(step)
        {
            const f16* rb = Rh_all + sBH + koff;
            f16x8 fr[32];
            Iss<0>::go(fr, rb);
            CONS_H(0, 24) CONS_H(1, 16) CONS_H(2, 8) CONS_H(3, 0)
        }
        f16x4 hv;
        #pragma unroll
        for (int j = 0; j < 4; ++j) {
            float ph = accH[j] + (float)gh4[j] + bbh[j];
            float e = __expf(2.f * ph);
            float th = 1.f - 2.f / (e + 1.f);
            float hn = zr[j] * h32r[j] + (1.f - zr[j]) * th;
            h32r[j] = hn;
            hv[j] = (f16)hn;
        }
        gstore8_cc(Hs + sBH + eoff, hv);
        if (step < T_STEPS - 1) wpub(flg, w, wg, 2u * (unsigned)step + 2u, lane);
    }
    asm volatile("s_waitcnt vmcnt(0)" ::: "memory");
#undef CONS_RZ
#undef CONS_H
}

// ---------------- output GEMM: out = Hs @ Wout^T + bout (fp32 out) ----------------
__global__ __launch_bounds__(256) void k_out_gemm(
    const f16* __restrict__ Hs, const float* __restrict__ Wout,
    const float* __restrict__ bout, float* __restrict__ out)
{
    __shared__ f16 As[128 * 40];
    __shared__ f16 Bs[128 * 40];

    const int t = threadIdx.x;
    const int lane = t & 63;
    const int w  = t >> 6;
    const int wm = w & 1, wn = w >> 1;
    const int bid = blockIdx.x;
    const int l   = (bid & 7) * 128 + (bid >> 3);
    const int rowBase = (l >> 2) * 128;
    const int colBase = (l & 3) * 128;

    const int srow = t >> 1;
    const int sk   = (t & 1) * 16;

    f32x4 acc[4][4] = {};

    for (int kt = 0; kt < H_DIM; kt += 32) {
        {
            const f16* ap = Hs + (size_t)(rowBase + srow) * H_DIM + kt + sk;
            *(f16x8*)&As[srow*40 + sk]     = *(const f16x8*)ap;
            *(f16x8*)&As[srow*40 + sk + 8] = *(const f16x8*)(ap + 8);
            const float* wp = Wout + (size_t)(colBase + srow) * H_DIM + kt + sk;
            f16x8 t0, t1;
            #pragma unroll
            for (int q = 0; q < 2; ++q) {
                float4 a = ((const float4*)wp)[q];
                t0[q*4+0] = (f16)a.x; t0[q*4+1] = (f16)a.y; t0[q*4+2] = (f16)a.z; t0[q*4+3] = (f16)a.w;
            }
            #pragma unroll
            for (int q = 0; q < 2; ++q) {
                float4 a = ((const float4*)wp)[q+2];
                t1[q*4+0] = (f16)a.x; t1[q*4+1] = (f16)a.y; t1[q*4+2] = (f16)a.z; t1[q*4+3] = (f16)a.w;
            }
            *(f16x8*)&Bs[srow*40 + sk]     = t0;
            *(f16x8*)&Bs[srow*40 + sk + 8] = t1;
        }
        __syncthreads();
        f16x8 af[4], bf[4];
        #pragma unroll
        for (int i = 0; i < 4; ++i)
            af[i] = *(const f16x8*)&As[(wm*64 + i*16 + (lane & 15))*40 + ((lane >> 4) * 8)];
        #pragma unroll
        for (int i = 0; i < 4; ++i)
            bf[i] = *(const f16x8*)&Bs[(wn*64 + i*16 + (lane & 15))*40 + ((lane >> 4) * 8)];
        #pragma unroll
        for (int i = 0; i < 4; ++i)
            #pragma unroll
            for (int j = 0; j < 4; ++j)
                acc[i][j] = __builtin_amdgcn_mfma_f32_16x16x32_f16(af[i], bf[j], acc[i][j], 0, 0, 0);
        __syncthreads();
    }
    #pragma unroll
    for (int i = 0; i < 4; ++i) {
        const int row = rowBase + wm*64 + i*16 + ((lane >> 4) * 4);
        #pragma unroll
        for (int j = 0; j < 4; ++j) {
            const int col = colBase + wn*64 + j*16 + (lane & 15);
            const float bb = bout[col];
            #pragma unroll
            for (int r = 0; r < 4; ++r)
                out[(size_t)(row + r) * O_DIM + col] = acc[i][j][r] + bb;
        }
    }
}

extern "C" void kernel_launch(void* const* d_in, const int* in_sizes, int n_in,
                              void* d_out, int out_size, void* d_ws, size_t ws_size,
                              hipStream_t stream) {
    const float* x    = (const float*)d_in[0];
    const float* rn   = (const float*)d_in[1];
    const float* zn   = (const float*)d_in[2];
    const float* hn   = (const float*)d_in[3];
    const float* Wxz  = (const float*)d_in[4];
    const float* Wxr  = (const float*)d_in[5];
    const float* Wxh  = (const float*)d_in[6];
    const float* Whz  = (const float*)d_in[7];
    const float* bz   = (const float*)d_in[8];
    const float* Whr  = (const float*)d_in[9];
    const float* br   = (const float*)d_in[10];
    const float* Whh  = (const float*)d_in[11];
    const float* bh   = (const float*)d_in[12];
    const float* Wout = (const float*)d_in[13];
    const float* bout = (const float*)d_in[14];
    float* out = (float*)d_out;

    char* ws = (char*)d_ws;
    size_t off = 0;
    f16* GR     = (f16*)(ws + off); off += (size_t)TBROWS * H_DIM * 2;  // 64 MB
    f16* GZ     = (f16*)(ws + off); off += (size_t)TBROWS * H_DIM * 2;
    f16* GH     = (f16*)(ws + off); off += (size_t)TBROWS * H_DIM * 2;
    f16* Hs     = (f16*)(ws + off); off += (size_t)TBROWS * H_DIM * 2;
    f16* Rh_all = (f16*)(ws + off); off += (size_t)TBROWS * H_DIM * 2;
    unsigned* flg = (unsigned*)(ws + off); off += (8 * NWG + 8 + 257) * 16 * 4;

    k_init<<<1, 256, 0, stream>>>(flg);
    k_fused<<<NWG + GBLK, 512, 0, stream>>>(
        x, rn, zn, hn, Wxr, Wxz, Wxh, Whr, Whz, Whh, br, bz, bh,
        GR, GZ, GH, Rh_all, Hs, flg);
    k_out_gemm<<<1024, 256, 0, stream>>>(Hs, Wout, bout, out);
}